// Round 2
// baseline (491.142 us; speedup 1.0000x reference)
//
#include <hip/hip_runtime.h>
#include <hip/hip_bf16.h>

#define NB 512
#define CIN 32
#define LEN 512
#define NE 8
#define NPOOL 16
#define DIN 16384
#define DOUT 768
#define HD 1024
#define F1 128

#define MT 256      // GEMM M tile (rows per expert tile)
#define NT 128      // GEMM N tile
#define KCH 4096    // K chunk per block
#define BK 64       // K step
#define NKC 4       // number of K chunks (4*4096 = 16384)

typedef __attribute__((ext_vector_type(4))) float f32x4;
typedef __attribute__((ext_vector_type(8))) short s16x8;

__device__ __forceinline__ float gelu_erf(float v) {
    return 0.5f * v * (1.0f + erff(v * 0.70710678118654752f));
}

__device__ __forceinline__ short f2bf(float f) {
    union { float f; unsigned u; } x; x.f = f;
    unsigned r = x.u + 0x7fffu + ((x.u >> 16) & 1u);   // round-nearest-even
    return (short)(r >> 16);
}

// ---------------- Kernel A: conv1d(k=3,pad=1) + GELU + avgpool(32) + BN ----------------
// grid = 512 (one block per batch row), block = 512
// thread t: pool bin p = t&15, channel pair cq = t>>4 -> co = 2cq, 2cq+1
__global__ __launch_bounds__(512) void krouter_conv(
    const float* __restrict__ x, const float* __restrict__ cw, const float* __restrict__ cb,
    const float* __restrict__ bng, const float* __restrict__ bnb,
    const float* __restrict__ bnm, const float* __restrict__ bnv,
    float* __restrict__ h)
{
    __shared__ float xs[CIN * LEN];   // 64KB, XOR-swizzled in 16B units along l
    int b = blockIdx.x;
    int t = threadIdx.x;

    const f32x4* xg = (const f32x4*)(x + (size_t)b * DIN);
    #pragma unroll
    for (int u = 0; u < 8; ++u) {
        int fi = t + 512 * u;          // float4 index, 4096 total
        f32x4 v = xg[fi];
        int e0 = fi * 4;
        int ci = e0 >> 9, l = e0 & 511;
        int byte = ci * 2048 + ((l * 4) ^ ((((unsigned)l >> 5) & 7u) << 4));
        *(f32x4*)((char*)xs + byte) = v;
    }
    __syncthreads();

    int p  = t & 15;
    int cq = t >> 4;                   // 0..31
    int co0 = cq * 2, co1 = co0 + 1;
    int l0 = p * 32;

    float sa[32], sb[32];
    #pragma unroll
    for (int i = 0; i < 32; ++i) { sa[i] = 0.f; sb[i] = 0.f; }

    for (int ci = 0; ci < CIN; ++ci) {
        float f[40];                   // covers l in [l0-4, l0+36)
        #pragma unroll
        for (int u = 0; u < 10; ++u) {
            int l = l0 - 4 + 4 * u;
            int lc = min(max(l, 0), 508);
            int byte = ci * 2048 + ((lc * 4) ^ ((((unsigned)lc >> 5) & 7u) << 4));
            f32x4 v = *(const f32x4*)((const char*)xs + byte);
            f[4*u+0] = v[0]; f[4*u+1] = v[1]; f[4*u+2] = v[2]; f[4*u+3] = v[3];
        }
        if (p == 0)  f[3]  = 0.f;      // left zero-pad x[-1]
        if (p == 15) f[36] = 0.f;      // right zero-pad x[512]
        float wa0 = cw[co0*96 + ci*3 + 0], wa1 = cw[co0*96 + ci*3 + 1], wa2 = cw[co0*96 + ci*3 + 2];
        float wb0 = cw[co1*96 + ci*3 + 0], wb1 = cw[co1*96 + ci*3 + 1], wb2 = cw[co1*96 + ci*3 + 2];
        #pragma unroll
        for (int i = 0; i < 32; ++i) {
            sa[i] = fmaf(f[i+3], wa0, fmaf(f[i+4], wa1, fmaf(f[i+5], wa2, sa[i])));
            sb[i] = fmaf(f[i+3], wb0, fmaf(f[i+4], wb1, fmaf(f[i+5], wb2, sb[i])));
        }
    }

    float ba = cb[co0], bbv = cb[co1];
    float ma = 0.f, mb = 0.f;
    #pragma unroll
    for (int i = 0; i < 32; ++i) { ma += gelu_erf(sa[i] + ba); mb += gelu_erf(sb[i] + bbv); }
    ma *= (1.f / 32.f); mb *= (1.f / 32.f);

    int oa = co0 * NPOOL + p, ob = co1 * NPOOL + p;
    float ra = (ma - bnm[oa]) * rsqrtf(bnv[oa] + 1e-5f) * bng[oa] + bnb[oa];
    float rb = (mb - bnm[ob]) * rsqrtf(bnv[ob] + 1e-5f) * bng[ob] + bnb[ob];
    h[(size_t)b * HD + oa] = ra;
    h[(size_t)b * HD + ob] = rb;
}

// ---------------- Kernel B: fc1+GELU, fc2, gumbel softmax, top-2, expert row lists ----------
// grid = 64, block = 256; each block handles 8 batch rows
__global__ __launch_bounds__(256) void krouter_fc(
    const float* __restrict__ h, const float* __restrict__ f1w, const float* __restrict__ f1b,
    const float* __restrict__ f2w, const float* __restrict__ f2b,
    const float* __restrict__ gu,
    int* __restrict__ top2e, float* __restrict__ top2w,
    int* __restrict__ cnt, int* __restrict__ rowlist, float* __restrict__ roww)
{
    __shared__ float hs[8 * HD];     // 32KB
    __shared__ float h1s[8 * F1];    // 4KB
    __shared__ float lg[8 * NE];

    int bb = blockIdx.x * 8;
    int t = threadIdx.x;

    const f32x4* hg = (const f32x4*)(h + (size_t)bb * HD);
    f32x4* hs4 = (f32x4*)hs;
    #pragma unroll
    for (int u = 0; u < 8; ++u) hs4[t + 256 * u] = hg[t + 256 * u];
    __syncthreads();

    // fc1: 8b x 128j outputs; thread t: j = t&127, handles 4 b's (pr = t>>7 selects half)
    int j = t & 127;
    int pr = t >> 7;
    float acc[4] = {0.f, 0.f, 0.f, 0.f};
    const f32x4* w4 = (const f32x4*)(f1w + (size_t)j * HD);
    for (int k4 = 0; k4 < 256; ++k4) {
        f32x4 w = w4[k4];
        #pragma unroll
        for (int g = 0; g < 4; ++g) {
            f32x4 hv = hs4[(pr * 4 + g) * 256 + k4];
            acc[g] += w[0]*hv[0] + w[1]*hv[1] + w[2]*hv[2] + w[3]*hv[3];
        }
    }
    float bj = f1b[j];
    #pragma unroll
    for (int g = 0; g < 4; ++g) h1s[(pr * 4 + g) * F1 + j] = gelu_erf(acc[g] + bj);
    __syncthreads();

    if (t < 64) {
        int bi = t >> 3, e = t & 7;
        float s = f2b[e];
        const float* w = f2w + e * F1;
        const float* hh = h1s + bi * F1;
        #pragma unroll 8
        for (int k = 0; k < F1; ++k) s += hh[k] * w[k];
        lg[bi * NE + e] = s;
    }
    __syncthreads();

    if (t < 8) {
        int bi = t; int b = bb + bi;
        float r[NE];
        float mx = -1e30f;
        #pragma unroll
        for (int e = 0; e < NE; ++e) {
            float g = -logf(-logf(gu[b * NE + e]));
            r[e] = lg[bi * NE + e] + g;     // TAU = 1
            mx = fmaxf(mx, r[e]);
        }
        float sum = 0.f;
        #pragma unroll
        for (int e = 0; e < NE; ++e) { r[e] = expf(r[e] - mx); sum += r[e]; }
        float inv = 1.f / sum;
        #pragma unroll
        for (int e = 0; e < NE; ++e) r[e] *= inv;
        int e0 = 0; float v0 = r[0];
        #pragma unroll
        for (int e = 1; e < NE; ++e) if (r[e] > v0) { v0 = r[e]; e0 = e; }
        int e1 = -1; float v1 = -1.f;
        #pragma unroll
        for (int e = 0; e < NE; ++e) { if (e == e0) continue; if (r[e] > v1) { v1 = r[e]; e1 = e; } }
        float den = v0 + v1 + 1e-8f;
        float w0 = v0 / den, w1 = v1 / den;
        top2e[b * 2 + 0] = e0; top2e[b * 2 + 1] = e1;
        top2w[b * 2 + 0] = w0; top2w[b * 2 + 1] = w1;
        int p0 = atomicAdd(&cnt[e0], 1);
        rowlist[e0 * NB + p0] = b * 2 + 0; roww[e0 * NB + p0] = w0;
        int p1 = atomicAdd(&cnt[e1], 1);
        rowlist[e1 * NB + p1] = b * 2 + 1; roww[e1 * NB + p1] = w1;
    }
}

// ---------------- Kernel C: gathered expert GEMM, bf16 MFMA, fp32->bf16 on the fly -------
// grid = 8e * 2mt * 6nt * 4kc = 384 blocks, block = 512 (8 waves: 4m x 2n)
__global__ __launch_bounds__(512) void kgemm(
    const float* __restrict__ x, const float* __restrict__ ew,
    const int* __restrict__ cnt, const int* __restrict__ rowlist, const float* __restrict__ roww,
    float* __restrict__ ypart)
{
    int bid = blockIdx.x;
    int kc = bid & 3;
    int nt = (bid >> 2) % 6;
    int emt = bid / 24;
    int mt = emt & 1;
    int e  = emt >> 1;

    int cn = cnt[e];
    int row0 = mt * MT;
    if (row0 >= cn) return;
    int mloc = min(MT, cn - row0);

    __shared__ __align__(16) short As[MT * BK];   // 32KB: row r stride 128B, XOR swizzle
    __shared__ __align__(16) short Bs[NT * BK];   // 16KB: row n stride 128B (W^T tile)

    int t = threadIdx.x;
    int wid = t >> 6;
    int lane = t & 63;
    int wm = wid >> 1, wn = wid & 1;

    // A staging: thread t -> row ar = t>>1, half ah = t&1 (32 floats each)
    int ar = t >> 1, ah = t & 1;
    bool aval = ar < mloc;
    int ab = aval ? (rowlist[e * NB + row0 + ar] >> 1) : 0;
    const float* axp = x + (size_t)ab * DIN + kc * KCH + ah * 32;

    // B staging: thread t -> col n = t&127, k-group bkg = t>>7 (16 k's each)
    int bn = t & 127, bkg = t >> 7;
    const float* bwp = ew + (size_t)e * DIN * DOUT + (size_t)(kc * KCH + bkg * 16) * DOUT + nt * NT + bn;

    f32x4 acc[4][4];
    #pragma unroll
    for (int i = 0; i < 4; ++i)
        #pragma unroll
        for (int jj = 0; jj < 4; ++jj) acc[i][jj] = (f32x4){0.f, 0.f, 0.f, 0.f};

    for (int s = 0; s < KCH / BK; ++s) {
        // ---- stage A tile (256 x 64 fp32 -> bf16) ----
        {
            const f32x4* src = (const f32x4*)(axp + s * BK);
            #pragma unroll
            for (int u = 0; u < 4; ++u) {
                f32x4 v0 = aval ? src[2*u]   : (f32x4){0.f,0.f,0.f,0.f};
                f32x4 v1 = aval ? src[2*u+1] : (f32x4){0.f,0.f,0.f,0.f};
                s16x8 pk;
                pk[0]=f2bf(v0[0]); pk[1]=f2bf(v0[1]); pk[2]=f2bf(v0[2]); pk[3]=f2bf(v0[3]);
                pk[4]=f2bf(v1[0]); pk[5]=f2bf(v1[1]); pk[6]=f2bf(v1[2]); pk[7]=f2bf(v1[3]);
                int col = ah * 32 + u * 8;
                *(s16x8*)((char*)As + ar * 128 + ((col * 2) ^ ((ar & 7) << 4))) = pk;
            }
        }
        // ---- stage B tile transposed (64k x 128n fp32 -> Bs[n][k] bf16) ----
        {
            #pragma unroll
            for (int u = 0; u < 2; ++u) {
                s16x8 pk;
                #pragma unroll
                for (int i = 0; i < 8; ++i)
                    pk[i] = f2bf(bwp[(size_t)(s * BK + u * 8 + i) * DOUT]);
                int col = bkg * 16 + u * 8;
                *(s16x8*)((char*)Bs + bn * 128 + ((col * 2) ^ ((bn & 7) << 4))) = pk;
            }
        }
        __syncthreads();

        // ---- compute: 2 x (K=32) MFMA steps ----
        int g = lane >> 4;
        #pragma unroll
        for (int kk = 0; kk < 2; ++kk) {
            int colb = (kk * 32 + g * 8) * 2;   // byte offset of this lane-group's 8 k's
            s16x8 af[4], bf_[4];
            #pragma unroll
            for (int mi = 0; mi < 4; ++mi) {
                int m = wm * 64 + mi * 16 + (lane & 15);
                af[mi] = *(const s16x8*)((const char*)As + m * 128 + (colb ^ ((m & 7) << 4)));
            }
            #pragma unroll
            for (int ni = 0; ni < 4; ++ni) {
                int n = wn * 64 + ni * 16 + (lane & 15);
                bf_[ni] = *(const s16x8*)((const char*)Bs + n * 128 + (colb ^ ((n & 7) << 4)));
            }
            #pragma unroll
            for (int mi = 0; mi < 4; ++mi)
                #pragma unroll
                for (int ni = 0; ni < 4; ++ni)
                    acc[mi][ni] = __builtin_amdgcn_mfma_f32_16x16x32_bf16(af[mi], bf_[ni], acc[mi][ni], 0, 0, 0);
        }
        __syncthreads();
    }

    // ---- epilogue: apply gate weight, scatter to per-(slot,kc) partial plane ----
    int g = lane >> 4;
    #pragma unroll
    for (int mi = 0; mi < 4; ++mi) {
        #pragma unroll
        for (int rg = 0; rg < 4; ++rg) {
            int m = wm * 64 + mi * 16 + g * 4 + rg;
            if (m < mloc) {
                int ent = rowlist[e * NB + row0 + m];
                float wgt = roww[e * NB + row0 + m];
                int ob = ent >> 1, slot = ent & 1;
                float* dst = ypart + ((size_t)(slot * 4 + kc) * NB + ob) * DOUT + nt * NT + wn * 64 + (lane & 15);
                #pragma unroll
                for (int ni = 0; ni < 4; ++ni)
                    dst[ni * 16] = acc[mi][ni][rg] * wgt;
            }
        }
    }
}

// ---------------- Kernel D: combine 8 partial planes + weighted expert bias ----------------
// grid = (3, 512), block = 256
__global__ __launch_bounds__(256) void kcombine(
    const float* __restrict__ ypart,
    const int* __restrict__ top2e, const float* __restrict__ top2w,
    const float* __restrict__ eb, float* __restrict__ out)
{
    int b = blockIdx.y;
    int n = blockIdx.x * 256 + threadIdx.x;
    float s = 0.f;
    #pragma unroll
    for (int p = 0; p < 8; ++p) s += ypart[((size_t)p * NB + b) * DOUT + n];
    int e0 = top2e[b * 2], e1 = top2e[b * 2 + 1];
    float w0 = top2w[b * 2], w1 = top2w[b * 2 + 1];
    s += w0 * eb[e0 * DOUT + n] + w1 * eb[e1 * DOUT + n];
    out[(size_t)b * DOUT + n] = s;
}

extern "C" void kernel_launch(void* const* d_in, const int* in_sizes, int n_in,
                              void* d_out, int out_size, void* d_ws, size_t ws_size,
                              hipStream_t stream)
{
    const float* x   = (const float*)d_in[0];
    const float* gu  = (const float*)d_in[1];
    const float* cw  = (const float*)d_in[2];
    const float* cb  = (const float*)d_in[3];
    const float* bng = (const float*)d_in[4];
    const float* bnb = (const float*)d_in[5];
    const float* bnm = (const float*)d_in[6];
    const float* bnv = (const float*)d_in[7];
    const float* f1w = (const float*)d_in[8];
    const float* f1b = (const float*)d_in[9];
    const float* f2w = (const float*)d_in[10];
    const float* f2b = (const float*)d_in[11];
    const float* ew  = (const float*)d_in[12];
    const float* eb  = (const float*)d_in[13];

    char* ws = (char*)d_ws;
    size_t off = 0;
    float* h       = (float*)(ws + off); off += (size_t)NB * HD * 4;      // 2 MB
    int*   top2e   = (int*)(ws + off);   off += (size_t)NB * 2 * 4;
    float* top2w   = (float*)(ws + off); off += (size_t)NB * 2 * 4;
    int*   cnt     = (int*)(ws + off);   off += 256;
    int*   rowlist = (int*)(ws + off);   off += (size_t)NE * NB * 4;
    float* roww    = (float*)(ws + off); off += (size_t)NE * NB * 4;
    float* ypart   = (float*)(ws + off); off += (size_t)8 * NB * DOUT * 4; // 12.6 MB

    hipMemsetAsync(cnt, 0, NE * sizeof(int), stream);
    krouter_conv<<<NB, 512, 0, stream>>>(x, cw, cb, bng, bnb, bnm, bnv, h);
    krouter_fc<<<NB / 8, 256, 0, stream>>>(h, f1w, f1b, f2w, f2b, gu,
                                           top2e, top2w, cnt, rowlist, roww);
    kgemm<<<NE * 2 * 6 * 4, 512, 0, stream>>>(x, ew, cnt, rowlist, roww, ypart);
    kcombine<<<dim3(3, NB), 256, 0, stream>>>(ypart, top2e, top2w, eb, (float*)d_out);
}

// Round 3
// 254.177 us; speedup vs baseline: 1.9323x; 1.9323x over previous
//
#include <hip/hip_runtime.h>
#include <hip/hip_bf16.h>

#define NB 512
#define CIN 32
#define LEN 512
#define NE 8
#define NPOOL 16
#define DIN 16384
#define DOUT 768
#define HD 1024
#define F1 128

#define MT 256      // GEMM M tile (covers an expert's rows; loop if cn>256)
#define NT 128      // GEMM N tile
#define BK 64       // K step

typedef __attribute__((ext_vector_type(4))) float f32x4;
typedef __attribute__((ext_vector_type(8))) short s16x8;
typedef __attribute__((ext_vector_type(4))) unsigned int u32x4;

__device__ __forceinline__ float gelu_erf(float v) {
    return 0.5f * v * (1.0f + erff(v * 0.70710678118654752f));
}

__device__ __forceinline__ unsigned cvt_pk(float lo, float hi) {
    unsigned r;
    asm volatile("v_cvt_pk_bf16_f32 %0, %1, %2" : "=v"(r) : "v"(lo), "v"(hi));
    return r;
}

// ---------------- Kernel A: conv1d(k=3,pad=1) + GELU + avgpool(32) + BN ----------------
__global__ __launch_bounds__(512) void krouter_conv(
    const float* __restrict__ x, const float* __restrict__ cw, const float* __restrict__ cb,
    const float* __restrict__ bng, const float* __restrict__ bnb,
    const float* __restrict__ bnm, const float* __restrict__ bnv,
    float* __restrict__ h)
{
    __shared__ float xs[CIN * LEN];   // 64KB, XOR-swizzled in 16B units along l
    int b = blockIdx.x;
    int t = threadIdx.x;

    const f32x4* xg = (const f32x4*)(x + (size_t)b * DIN);
    #pragma unroll
    for (int u = 0; u < 8; ++u) {
        int fi = t + 512 * u;
        f32x4 v = xg[fi];
        int e0 = fi * 4;
        int ci = e0 >> 9, l = e0 & 511;
        int byte = ci * 2048 + ((l * 4) ^ ((((unsigned)l >> 5) & 7u) << 4));
        *(f32x4*)((char*)xs + byte) = v;
    }
    __syncthreads();

    int p  = t & 15;
    int cq = t >> 4;
    int co0 = cq * 2, co1 = co0 + 1;
    int l0 = p * 32;

    float sa[32], sb[32];
    #pragma unroll
    for (int i = 0; i < 32; ++i) { sa[i] = 0.f; sb[i] = 0.f; }

    for (int ci = 0; ci < CIN; ++ci) {
        float f[40];
        #pragma unroll
        for (int u = 0; u < 10; ++u) {
            int l = l0 - 4 + 4 * u;
            int lc = min(max(l, 0), 508);
            int byte = ci * 2048 + ((lc * 4) ^ ((((unsigned)lc >> 5) & 7u) << 4));
            f32x4 v = *(const f32x4*)((const char*)xs + byte);
            f[4*u+0] = v[0]; f[4*u+1] = v[1]; f[4*u+2] = v[2]; f[4*u+3] = v[3];
        }
        if (p == 0)  f[3]  = 0.f;
        if (p == 15) f[36] = 0.f;
        float wa0 = cw[co0*96 + ci*3 + 0], wa1 = cw[co0*96 + ci*3 + 1], wa2 = cw[co0*96 + ci*3 + 2];
        float wb0 = cw[co1*96 + ci*3 + 0], wb1 = cw[co1*96 + ci*3 + 1], wb2 = cw[co1*96 + ci*3 + 2];
        #pragma unroll
        for (int i = 0; i < 32; ++i) {
            sa[i] = fmaf(f[i+3], wa0, fmaf(f[i+4], wa1, fmaf(f[i+5], wa2, sa[i])));
            sb[i] = fmaf(f[i+3], wb0, fmaf(f[i+4], wb1, fmaf(f[i+5], wb2, sb[i])));
        }
    }

    float ba = cb[co0], bbv = cb[co1];
    float ma = 0.f, mb = 0.f;
    #pragma unroll
    for (int i = 0; i < 32; ++i) { ma += gelu_erf(sa[i] + ba); mb += gelu_erf(sb[i] + bbv); }
    ma *= (1.f / 32.f); mb *= (1.f / 32.f);

    int oa = co0 * NPOOL + p, ob = co1 * NPOOL + p;
    float ra = (ma - bnm[oa]) * rsqrtf(bnv[oa] + 1e-5f) * bng[oa] + bnb[oa];
    float rb = (mb - bnm[ob]) * rsqrtf(bnv[ob] + 1e-5f) * bng[ob] + bnb[ob];
    h[(size_t)b * HD + oa] = ra;
    h[(size_t)b * HD + ob] = rb;
}

// ---------------- Kernel B: fc1+GELU, fc2, gumbel softmax, top-2, expert row lists ----------
__global__ __launch_bounds__(256) void krouter_fc(
    const float* __restrict__ h, const float* __restrict__ f1w, const float* __restrict__ f1b,
    const float* __restrict__ f2w, const float* __restrict__ f2b,
    const float* __restrict__ gu,
    int* __restrict__ top2e, float* __restrict__ top2w,
    int* __restrict__ cnt, int* __restrict__ rowlist, float* __restrict__ roww)
{
    __shared__ float hs[8 * HD];
    __shared__ float h1s[8 * F1];
    __shared__ float lg[8 * NE];

    int bb = blockIdx.x * 8;
    int t = threadIdx.x;

    const f32x4* hg = (const f32x4*)(h + (size_t)bb * HD);
    f32x4* hs4 = (f32x4*)hs;
    #pragma unroll
    for (int u = 0; u < 8; ++u) hs4[t + 256 * u] = hg[t + 256 * u];
    __syncthreads();

    int j = t & 127;
    int pr = t >> 7;
    float acc[4] = {0.f, 0.f, 0.f, 0.f};
    const f32x4* w4 = (const f32x4*)(f1w + (size_t)j * HD);
    for (int k4 = 0; k4 < 256; ++k4) {
        f32x4 w = w4[k4];
        #pragma unroll
        for (int g = 0; g < 4; ++g) {
            f32x4 hv = hs4[(pr * 4 + g) * 256 + k4];
            acc[g] += w[0]*hv[0] + w[1]*hv[1] + w[2]*hv[2] + w[3]*hv[3];
        }
    }
    float bj = f1b[j];
    #pragma unroll
    for (int g = 0; g < 4; ++g) h1s[(pr * 4 + g) * F1 + j] = gelu_erf(acc[g] + bj);
    __syncthreads();

    if (t < 64) {
        int bi = t >> 3, e = t & 7;
        float s = f2b[e];
        const float* w = f2w + e * F1;
        const float* hh = h1s + bi * F1;
        #pragma unroll 8
        for (int k = 0; k < F1; ++k) s += hh[k] * w[k];
        lg[bi * NE + e] = s;
    }
    __syncthreads();

    if (t < 8) {
        int bi = t; int b = bb + bi;
        float r[NE];
        float mx = -1e30f;
        #pragma unroll
        for (int e = 0; e < NE; ++e) {
            float g = -logf(-logf(gu[b * NE + e]));
            r[e] = lg[bi * NE + e] + g;
            mx = fmaxf(mx, r[e]);
        }
        float sum = 0.f;
        #pragma unroll
        for (int e = 0; e < NE; ++e) { r[e] = expf(r[e] - mx); sum += r[e]; }
        float inv = 1.f / sum;
        #pragma unroll
        for (int e = 0; e < NE; ++e) r[e] *= inv;
        int e0 = 0; float v0 = r[0];
        #pragma unroll
        for (int e = 1; e < NE; ++e) if (r[e] > v0) { v0 = r[e]; e0 = e; }
        int e1 = -1; float v1 = -1.f;
        #pragma unroll
        for (int e = 0; e < NE; ++e) { if (e == e0) continue; if (r[e] > v1) { v1 = r[e]; e1 = e; } }
        float den = v0 + v1 + 1e-8f;
        float w0 = v0 / den, w1 = v1 / den;
        top2e[b * 2 + 0] = e0; top2e[b * 2 + 1] = e1;
        top2w[b * 2 + 0] = w0; top2w[b * 2 + 1] = w1;
        int p0 = atomicAdd(&cnt[e0], 1);
        rowlist[e0 * NB + p0] = b * 2 + 0; roww[e0 * NB + p0] = w0;
        int p1 = atomicAdd(&cnt[e1], 1);
        rowlist[e1 * NB + p1] = b * 2 + 1; roww[e1 * NB + p1] = w1;
    }
}

// ---------------- Kernel C: gathered expert GEMM, bf16 MFMA, reg-prefetch pipeline -------
// grid = 8e * 6nt * nkc, block = 512 (8 waves: 4m x 2n)
__global__ __launch_bounds__(512) void kgemm(
    const float* __restrict__ x, const float* __restrict__ ew,
    const int* __restrict__ cnt, const int* __restrict__ rowlist, const float* __restrict__ roww,
    float* __restrict__ ypart, int nkc, int kch)
{
    int bid = blockIdx.x;
    int kc = bid % nkc;
    int nt = (bid / nkc) % 6;
    int e  = bid / (nkc * 6);
    int cn = cnt[e];
    if (cn <= 0) return;

    __shared__ __align__(16) short As[MT * BK];   // 32KB, XOR swizzle
    __shared__ __align__(16) short Bs[NT * BK];   // 16KB, W^T tile

    int t = threadIdx.x;
    int wid = t >> 6, lane = t & 63;
    int wm = wid >> 1, wn = wid & 1;
    int g = lane >> 4;
    int NS = kch / BK;
    int k0 = kc * kch;

    // B staging assignment: col n = t&127, k-group = t>>7 (16 k's each)
    int bn = t & 127, bkg = t >> 7;
    const float* bwp = ew + (size_t)e * ((size_t)DIN * DOUT)
                          + (size_t)(k0 + bkg * 16) * DOUT + nt * NT + bn;

    for (int row0 = 0; row0 < cn; row0 += MT) {
        int mloc = min(MT, cn - row0);

        // A staging assignment: row = t>>1, half = t&1 (32 floats each)
        int ar = t >> 1, ah = t & 1;
        int arc = min(ar, mloc - 1);
        int ent_a = rowlist[e * NB + row0 + arc];
        const float* axp = x + (size_t)(ent_a >> 1) * DIN + k0 + ah * 32;
        bool ado = (ar < mloc);
        bool wact = (wm * 64 < mloc);

        f32x4 acc[4][4];
        #pragma unroll
        for (int i = 0; i < 4; ++i)
            #pragma unroll
            for (int jj = 0; jj < 4; ++jj) acc[i][jj] = (f32x4){0.f, 0.f, 0.f, 0.f};

        f32x4 Ar[8]; float Br[16];
        // prologue: prefetch s=0
        if (ado) {
            const f32x4* p = (const f32x4*)axp;
            #pragma unroll
            for (int u = 0; u < 8; ++u) Ar[u] = p[u];
        }
        #pragma unroll
        for (int u = 0; u < 2; ++u)
            #pragma unroll
            for (int i = 0; i < 8; ++i)
                Br[u*8+i] = bwp[(size_t)(u*8+i) * DOUT];

        for (int s = 0; s < NS; ++s) {
            // ---- convert + store tile s to LDS ----
            if (ado) {
                #pragma unroll
                for (int u = 0; u < 4; ++u) {
                    u32x4 pk;
                    pk[0] = cvt_pk(Ar[2*u][0], Ar[2*u][1]);
                    pk[1] = cvt_pk(Ar[2*u][2], Ar[2*u][3]);
                    pk[2] = cvt_pk(Ar[2*u+1][0], Ar[2*u+1][1]);
                    pk[3] = cvt_pk(Ar[2*u+1][2], Ar[2*u+1][3]);
                    int col = ah * 32 + u * 8;
                    *(u32x4*)((char*)As + ar * 128 + ((col * 2) ^ ((ar & 7) << 4))) = pk;
                }
            }
            {
                #pragma unroll
                for (int u = 0; u < 2; ++u) {
                    u32x4 pk;
                    pk[0] = cvt_pk(Br[u*8+0], Br[u*8+1]);
                    pk[1] = cvt_pk(Br[u*8+2], Br[u*8+3]);
                    pk[2] = cvt_pk(Br[u*8+4], Br[u*8+5]);
                    pk[3] = cvt_pk(Br[u*8+6], Br[u*8+7]);
                    int col = bkg * 16 + u * 8;
                    *(u32x4*)((char*)Bs + bn * 128 + ((col * 2) ^ ((bn & 7) << 4))) = pk;
                }
            }
            __syncthreads();

            // ---- prefetch tile s+1 into registers (hides latency under MFMA) ----
            if (s + 1 < NS) {
                if (ado) {
                    const f32x4* p = (const f32x4*)(axp + (s + 1) * BK);
                    #pragma unroll
                    for (int u = 0; u < 8; ++u) Ar[u] = p[u];
                }
                #pragma unroll
                for (int u = 0; u < 2; ++u)
                    #pragma unroll
                    for (int i = 0; i < 8; ++i)
                        Br[u*8+i] = bwp[(size_t)((s + 1) * BK + u*8 + i) * DOUT];
            }

            // ---- compute ----
            if (wact) {
                #pragma unroll
                for (int kk = 0; kk < 2; ++kk) {
                    int colb = (kk * 32 + g * 8) * 2;
                    s16x8 af[4], bfr[4];
                    #pragma unroll
                    for (int mi = 0; mi < 4; ++mi) {
                        int m = wm * 64 + mi * 16 + (lane & 15);
                        af[mi] = *(const s16x8*)((const char*)As + m * 128 + (colb ^ ((m & 7) << 4)));
                    }
                    #pragma unroll
                    for (int ni = 0; ni < 4; ++ni) {
                        int n = wn * 64 + ni * 16 + (lane & 15);
                        bfr[ni] = *(const s16x8*)((const char*)Bs + n * 128 + (colb ^ ((n & 7) << 4)));
                    }
                    #pragma unroll
                    for (int mi = 0; mi < 4; ++mi)
                        #pragma unroll
                        for (int ni = 0; ni < 4; ++ni)
                            acc[mi][ni] = __builtin_amdgcn_mfma_f32_16x16x32_bf16(af[mi], bfr[ni], acc[mi][ni], 0, 0, 0);
                }
            }
            __syncthreads();
        }

        // ---- epilogue: apply gate weight, scatter to per-(slot,kc) partial plane ----
        if (wact) {
            #pragma unroll
            for (int mi = 0; mi < 4; ++mi) {
                #pragma unroll
                for (int rg = 0; rg < 4; ++rg) {
                    int m = wm * 64 + mi * 16 + g * 4 + rg;
                    if (m < mloc) {
                        int ent = rowlist[e * NB + row0 + m];
                        float wgt = roww[e * NB + row0 + m];
                        int ob = ent >> 1, slot = ent & 1;
                        float* dst = ypart + ((size_t)(slot * nkc + kc) * NB + ob) * DOUT
                                   + nt * NT + wn * 64 + (lane & 15);
                        #pragma unroll
                        for (int ni = 0; ni < 4; ++ni)
                            dst[ni * 16] = acc[mi][ni][rg] * wgt;
                    }
                }
            }
        }
    }
}

// ---------------- Kernel D: combine partial planes + weighted expert bias ----------------
__global__ __launch_bounds__(256) void kcombine(
    const float* __restrict__ ypart,
    const int* __restrict__ top2e, const float* __restrict__ top2w,
    const float* __restrict__ eb, float* __restrict__ out, int nplanes)
{
    int b = blockIdx.y;
    int n = blockIdx.x * 256 + threadIdx.x;
    float s = 0.f;
    for (int p = 0; p < nplanes; ++p) s += ypart[((size_t)p * NB + b) * DOUT + n];
    int e0 = top2e[b * 2], e1 = top2e[b * 2 + 1];
    float w0 = top2w[b * 2], w1 = top2w[b * 2 + 1];
    s += w0 * eb[e0 * DOUT + n] + w1 * eb[e1 * DOUT + n];
    out[(size_t)b * DOUT + n] = s;
}

extern "C" void kernel_launch(void* const* d_in, const int* in_sizes, int n_in,
                              void* d_out, int out_size, void* d_ws, size_t ws_size,
                              hipStream_t stream)
{
    const float* x   = (const float*)d_in[0];
    const float* gu  = (const float*)d_in[1];
    const float* cw  = (const float*)d_in[2];
    const float* cb  = (const float*)d_in[3];
    const float* bng = (const float*)d_in[4];
    const float* bnb = (const float*)d_in[5];
    const float* bnm = (const float*)d_in[6];
    const float* bnv = (const float*)d_in[7];
    const float* f1w = (const float*)d_in[8];
    const float* f1b = (const float*)d_in[9];
    const float* f2w = (const float*)d_in[10];
    const float* f2b = (const float*)d_in[11];
    const float* ew  = (const float*)d_in[12];
    const float* eb  = (const float*)d_in[13];

    // K-split chosen by available workspace (32 planes needs ~53 MB total)
    int nkc = (ws_size >= (size_t)56 * 1024 * 1024) ? 16 : 8;
    int kch = DIN / nkc;

    char* ws = (char*)d_ws;
    size_t off = 0;
    float* h       = (float*)(ws + off); off += (size_t)NB * HD * 4;
    int*   top2e   = (int*)(ws + off);   off += (size_t)NB * 2 * 4;
    float* top2w   = (float*)(ws + off); off += (size_t)NB * 2 * 4;
    int*   cnt     = (int*)(ws + off);   off += 256;
    int*   rowlist = (int*)(ws + off);   off += (size_t)NE * NB * 4;
    float* roww    = (float*)(ws + off); off += (size_t)NE * NB * 4;
    float* ypart   = (float*)(ws + off); off += (size_t)2 * nkc * NB * DOUT * 4;

    hipMemsetAsync(cnt, 0, NE * sizeof(int), stream);
    krouter_conv<<<NB, 512, 0, stream>>>(x, cw, cb, bng, bnb, bnm, bnv, h);
    krouter_fc<<<NB / 8, 256, 0, stream>>>(h, f1w, f1b, f2w, f2b, gu,
                                           top2e, top2w, cnt, rowlist, roww);
    kgemm<<<NE * 6 * nkc, 512, 0, stream>>>(x, ew, cnt, rowlist, roww, ypart, nkc, kch);
    kcombine<<<dim3(3, NB), 256, 0, stream>>>(ypart, top2e, top2w, eb, (float*)d_out, 2 * nkc);
}